// Round 5
// baseline (183.183 us; speedup 1.0000x reference)
//
#include <hip/hip_runtime.h>

// GCN 2-layer forward on MI355X.
// out = Ahat @ (X W1) -> relu -> Ahat @ (H W2), Ahat = D^-1/2 (A+I) D^-1/2.
// CSR via two-level bucketed counting sort (coalesced writes, no global
// per-edge atomics). Layer-1 intermediate hs1 stored in bf16 (halves the
// dominant random-gather traffic); layer-1 aggregate uses 8 groups x 8
// lanes (8 edges in flight/wave) with fused (h1 @ W2)*dinv epilogue.

#define NBSHIFT 9
#define BUCKET_NODES 512
#define CAP 10240
#define CHA 8192
#define TA 512
#define TB 512
#define MAXNB 160

__device__ __forceinline__ unsigned bfpack(float a, float b) {
  unsigned ua = __float_as_uint(a), ub = __float_as_uint(b);
  ua += 0x7fffu + ((ua >> 16) & 1u);   // RNE to bf16
  ub += 0x7fffu + ((ub >> 16) & 1u);
  return (ua >> 16) | (ub & 0xffff0000u);
}

// ---------------- Pass A: coarse bucketing ----------------
__global__ void kA_zero(int* __restrict__ bucketCur, int NB) {
  int i = blockIdx.x * blockDim.x + threadIdx.x;
  if (i < NB) bucketCur[i] = 0;
}

__launch_bounds__(TA)
__global__ void kA_bucket(const int* __restrict__ src, const int* __restrict__ dst,
                          int* __restrict__ bucketCur, int* __restrict__ bucketArr,
                          int NB, int E) {
  __shared__ int stage[CHA];
  __shared__ unsigned char binOf[CHA];
  __shared__ int cnt[MAXNB];
  __shared__ int off[MAXNB];
  __shared__ int gpos[MAXNB];
  __shared__ int cursor[MAXNB];
  __shared__ int scanbuf[256];
  int t = threadIdx.x;
  int e0 = blockIdx.x * CHA;

  for (int i = t; i < NB; i += TA) cnt[i] = 0;
  __syncthreads();
  for (int i = t; i < CHA; i += TA) {
    int e = e0 + i;
    if (e < E) atomicAdd(&cnt[dst[e] >> NBSHIFT], 1);
  }
  __syncthreads();
  if (t < 256) scanbuf[t] = (t < NB) ? cnt[t] : 0;
  __syncthreads();
  for (int o = 1; o < 256; o <<= 1) {
    int add = (t < 256 && t >= o) ? scanbuf[t - o] : 0;
    __syncthreads();
    if (t < 256) scanbuf[t] += add;
    __syncthreads();
  }
  if (t < NB) {
    off[t] = scanbuf[t] - cnt[t];
    cursor[t] = off[t];
    gpos[t] = (cnt[t] > 0) ? atomicAdd(&bucketCur[t], cnt[t]) : 0;
  }
  __syncthreads();
  for (int i = t; i < CHA; i += TA) {
    int e = e0 + i;
    if (e < E) {
      int d = dst[e], s = src[e];
      int b = d >> NBSHIFT;
      int p = atomicAdd(&cursor[b], 1);
      stage[p] = (s << NBSHIFT) | (d & (BUCKET_NODES - 1));
      binOf[p] = (unsigned char)b;
    }
  }
  __syncthreads();
  int total = scanbuf[255];
  for (int i = t; i < total; i += TA) {
    int b = binOf[i];
    int destIdx = gpos[b] + (i - off[b]);
    if (destIdx < CAP) bucketArr[b * CAP + destIdx] = stage[i];
  }
}

// ---------------- Scan bucket totals ----------------
__global__ void kB_scan(const int* __restrict__ bucketCur, int* __restrict__ bucketBase,
                        int* __restrict__ rp, int NB, int N) {
  __shared__ int s[256];
  int t = threadIdx.x;
  int v = (t < NB) ? min(bucketCur[t], CAP) : 0;
  s[t] = v;
  __syncthreads();
  for (int o = 1; o < 256; o <<= 1) {
    int add = (t >= o) ? s[t - o] : 0;
    __syncthreads();
    s[t] += add;
    __syncthreads();
  }
  if (t < NB) bucketBase[t] = s[t] - v;  // exclusive
  if (t == NB - 1) {
    bucketBase[NB] = s[t];
    rp[N] = s[t];
  }
}

// ---------------- Pass B: per-bucket fine counting sort in LDS ----------------
__launch_bounds__(TB)
__global__ void kB_fill(const int* __restrict__ bucketArr, const int* __restrict__ bucketCur,
                        const int* __restrict__ bucketBase,
                        int* __restrict__ rp, float* __restrict__ dinv,
                        int* __restrict__ col, int N) {
  __shared__ int hist[BUCKET_NODES];
  __shared__ int noff[BUCKET_NODES];
  __shared__ int cur[BUCKET_NODES];
  __shared__ int colStage[CAP];
  int b = blockIdx.x;
  int t = threadIdx.x;
  int nE = min(bucketCur[b], CAP);
  int base = b * CAP;

  hist[t] = 0;
  __syncthreads();
  for (int i = t; i < nE; i += TB) {
    atomicAdd(&hist[bucketArr[base + i] & (BUCKET_NODES - 1)], 1);
  }
  __syncthreads();
  int myv = hist[t];
  noff[t] = myv;
  __syncthreads();
  for (int o = 1; o < BUCKET_NODES; o <<= 1) {
    int add = (t >= o) ? noff[t - o] : 0;
    __syncthreads();
    noff[t] += add;
    __syncthreads();
  }
  int excl = noff[t] - myv;
  cur[t] = excl;
  int gnode = b * BUCKET_NODES + t;
  if (gnode < N) {
    rp[gnode] = bucketBase[b] + excl;
    dinv[gnode] = rsqrtf((float)(myv + 1));  // +1 self loop
  }
  __syncthreads();
  for (int i = t; i < nE; i += TB) {
    int v = bucketArr[base + i];
    int p = atomicAdd(&cur[v & (BUCKET_NODES - 1)], 1);
    colStage[p] = v >> NBSHIFT;
  }
  __syncthreads();
  int gb = bucketBase[b];
  for (int i = t; i < nE; i += TB) col[gb + i] = colStage[i];
}

// ---------------- Dense compute ----------------
// hs1(bf16) = dinv[r] * (X @ W1). Register-tiled: block = 64 rows x 64 cols,
// thread = 4x4. Output packed to bf16 (row = 128 B).
__launch_bounds__(256)
__global__ void k_gemm64(const float4* __restrict__ X4, const float4* __restrict__ W4,
                         const float* __restrict__ dinv, uint2* __restrict__ outb,
                         int n) {
  __shared__ float4 Xs[64 * 17];
  __shared__ float4 Ws[64 * 16];
  int t = threadIdx.x;
  int base = blockIdx.x * 64;
  {
    int rr = t >> 2, q = t & 3;
    int r = base + rr;
    #pragma unroll
    for (int c = 0; c < 4; c++) {
      float4 v = make_float4(0.f, 0.f, 0.f, 0.f);
      if (r < n) v = X4[r * 16 + q * 4 + c];
      Xs[rr * 17 + q * 4 + c] = v;
      Ws[t + 256 * c] = W4[t + 256 * c];
    }
  }
  __syncthreads();

  int tx = t & 15, ty = t >> 4;
  float4 a0 = make_float4(0.f, 0.f, 0.f, 0.f), a1 = a0, a2 = a0, a3 = a0;
  #pragma unroll
  for (int kb = 0; kb < 16; kb++) {
    float4 x0 = Xs[(ty * 4 + 0) * 17 + kb];
    float4 x1 = Xs[(ty * 4 + 1) * 17 + kb];
    float4 x2 = Xs[(ty * 4 + 2) * 17 + kb];
    float4 x3 = Xs[(ty * 4 + 3) * 17 + kb];
    float4 w0 = Ws[(kb * 4 + 0) * 16 + tx];
    float4 w1 = Ws[(kb * 4 + 1) * 16 + tx];
    float4 w2 = Ws[(kb * 4 + 2) * 16 + tx];
    float4 w3 = Ws[(kb * 4 + 3) * 16 + tx];
    #define FMA4(A, XS) \
      A.x = fmaf(XS.x, w0.x, A.x); A.y = fmaf(XS.x, w0.y, A.y); \
      A.z = fmaf(XS.x, w0.z, A.z); A.w = fmaf(XS.x, w0.w, A.w); \
      A.x = fmaf(XS.y, w1.x, A.x); A.y = fmaf(XS.y, w1.y, A.y); \
      A.z = fmaf(XS.y, w1.z, A.z); A.w = fmaf(XS.y, w1.w, A.w); \
      A.x = fmaf(XS.z, w2.x, A.x); A.y = fmaf(XS.z, w2.y, A.y); \
      A.z = fmaf(XS.z, w2.z, A.z); A.w = fmaf(XS.z, w2.w, A.w); \
      A.x = fmaf(XS.w, w3.x, A.x); A.y = fmaf(XS.w, w3.y, A.y); \
      A.z = fmaf(XS.w, w3.z, A.z); A.w = fmaf(XS.w, w3.w, A.w);
    FMA4(a0, x0) FMA4(a1, x1) FMA4(a2, x2) FMA4(a3, x3)
    #undef FMA4
  }
  #pragma unroll
  for (int i = 0; i < 4; i++) {
    int r = base + ty * 4 + i;
    if (r < n) {
      float s = dinv[r];
      float4 a = (i == 0) ? a0 : (i == 1) ? a1 : (i == 2) ? a2 : a3;
      uint2 pk;
      pk.x = bfpack(a.x * s, a.y * s);
      pk.y = bfpack(a.z * s, a.w * s);
      outb[r * 16 + tx] = pk;   // row stride 16 uint2 = 128 B
    }
  }
}

// Layer-1 aggregate + relu + fused (h1 @ W2)*dinv epilogue.
// One wave/node; 8 groups x 8 lanes; each lane loads 16 B = 8 bf16 cols.
__launch_bounds__(256)
__global__ void k_agg64_w2(const uint4* __restrict__ hsb,    // [n*8] bf16 rows
                           const int* __restrict__ rp,
                           const int* __restrict__ col,
                           const float* __restrict__ dinv,
                           const float* __restrict__ b1,
                           const float* __restrict__ W2,     // 64x16
                           float* __restrict__ hs2,          // [n*16] f32
                           int n) {
  int lane = threadIdx.x & 63;
  int c = lane & 7;      // octet: cols 8c..8c+7
  int sub = lane >> 3;   // group 0..7; owns output cols 2sub, 2sub+1
  int node = (blockIdx.x * blockDim.x + threadIdx.x) >> 6;
  if (node >= n) return;

  // per-lane W2 slice: k in [8c,8c+8), j in {2sub, 2sub+1}
  float w2a[8], w2b[8];
  #pragma unroll
  for (int i = 0; i < 8; i++) {
    float2 w = ((const float2*)W2)[(8 * c + i) * 8 + sub];
    w2a[i] = w.x; w2b[i] = w.y;
  }
  float4 b1lo = ((const float4*)b1)[2 * c];
  float4 b1hi = ((const float4*)b1)[2 * c + 1];

  int s0 = rp[node], s1 = rp[node + 1];
  int dt = s1 - s0 + 1;  // [self] + col[s0..s1)
  float a0 = 0.f, a1 = 0.f, a2 = 0.f, a3 = 0.f;
  float a4 = 0.f, a5 = 0.f, a6 = 0.f, a7 = 0.f;
  int t = sub;
  int idx = 0;
  if (t < dt) idx = (t == 0) ? node : col[s0 + t - 1];
  while (t < dt) {
    int curi = idx;
    int tn = t + 8;
    if (tn < dt) idx = col[s0 + tn - 1];
    uint4 u = hsb[curi * 8 + c];
    a0 += __uint_as_float(u.x << 16);
    a1 += __uint_as_float(u.x & 0xffff0000u);
    a2 += __uint_as_float(u.y << 16);
    a3 += __uint_as_float(u.y & 0xffff0000u);
    a4 += __uint_as_float(u.z << 16);
    a5 += __uint_as_float(u.z & 0xffff0000u);
    a6 += __uint_as_float(u.w << 16);
    a7 += __uint_as_float(u.w & 0xffff0000u);
    t = tn;
  }
  #pragma unroll
  for (int m = 8; m <= 32; m <<= 1) {
    a0 += __shfl_xor(a0, m); a1 += __shfl_xor(a1, m);
    a2 += __shfl_xor(a2, m); a3 += __shfl_xor(a3, m);
    a4 += __shfl_xor(a4, m); a5 += __shfl_xor(a5, m);
    a6 += __shfl_xor(a6, m); a7 += __shfl_xor(a7, m);
  }
  float dv = dinv[node];
  float h0 = fmaxf(a0 * dv + b1lo.x, 0.f);
  float h1 = fmaxf(a1 * dv + b1lo.y, 0.f);
  float h2 = fmaxf(a2 * dv + b1lo.z, 0.f);
  float h3 = fmaxf(a3 * dv + b1lo.w, 0.f);
  float h4 = fmaxf(a4 * dv + b1hi.x, 0.f);
  float h5 = fmaxf(a5 * dv + b1hi.y, 0.f);
  float h6 = fmaxf(a6 * dv + b1hi.z, 0.f);
  float h7 = fmaxf(a7 * dv + b1hi.w, 0.f);

  float p0 = h0 * w2a[0] + h1 * w2a[1] + h2 * w2a[2] + h3 * w2a[3]
           + h4 * w2a[4] + h5 * w2a[5] + h6 * w2a[6] + h7 * w2a[7];
  float p1 = h0 * w2b[0] + h1 * w2b[1] + h2 * w2b[2] + h3 * w2b[3]
           + h4 * w2b[4] + h5 * w2b[5] + h6 * w2b[6] + h7 * w2b[7];
  #pragma unroll
  for (int m = 1; m <= 4; m <<= 1) {
    p0 += __shfl_xor(p0, m);
    p1 += __shfl_xor(p1, m);
  }
  if (c == 0) {
    ((float2*)hs2)[node * 8 + sub] = make_float2(p0 * dv, p1 * dv);
  }
}

// Layer-2 aggregate: one wave per node, 16 groups x 4 lanes. Final output.
__launch_bounds__(256)
__global__ void k_agg16(const float4* __restrict__ hs2_4,  // [n*4]
                        const int* __restrict__ rp,
                        const int* __restrict__ col,
                        const float* __restrict__ dinv,
                        const float* __restrict__ b2,
                        float4* __restrict__ out4,          // [n*4]
                        int n) {
  int lane = threadIdx.x & 63;
  int c = lane & 3;
  int sub = lane >> 2;
  int node = (blockIdx.x * blockDim.x + threadIdx.x) >> 6;
  if (node >= n) return;

  int s0 = rp[node], s1 = rp[node + 1];
  int dt = s1 - s0 + 1;
  float ax = 0.f, ay = 0.f, az = 0.f, aw = 0.f;
  int t = sub;
  int idx = 0;
  if (t < dt) idx = (t == 0) ? node : col[s0 + t - 1];
  while (t < dt) {
    int curi = idx;
    int tn = t + 16;
    if (tn < dt) idx = col[s0 + tn - 1];
    float4 row = hs2_4[curi * 4 + c];
    ax += row.x; ay += row.y; az += row.z; aw += row.w;
    t = tn;
  }
  #pragma unroll
  for (int m = 4; m <= 32; m <<= 1) {
    ax += __shfl_xor(ax, m);
    ay += __shfl_xor(ay, m);
    az += __shfl_xor(az, m);
    aw += __shfl_xor(aw, m);
  }
  if (sub == 0) {
    float dv = dinv[node];
    float4 b24 = ((const float4*)b2)[c];
    float4 o;
    o.x = ax * dv + b24.x;
    o.y = ay * dv + b24.y;
    o.z = az * dv + b24.z;
    o.w = aw * dv + b24.w;
    out4[node * 4 + c] = o;
  }
}

extern "C" void kernel_launch(void* const* d_in, const int* in_sizes, int n_in,
                              void* d_out, int out_size, void* d_ws, size_t ws_size,
                              hipStream_t stream) {
  const float* x  = (const float*)d_in[0];
  const int* edges = (const int*)d_in[1];
  const float* W1 = (const float*)d_in[2];
  const float* b1 = (const float*)d_in[3];
  const float* W2 = (const float*)d_in[4];
  const float* b2 = (const float*)d_in[5];
  float* out = (float*)d_out;

  const int N = in_sizes[0] / 64;
  const int E = in_sizes[1] / 2;
  const int* src = edges;
  const int* dst = edges + E;
  const int NB = (N + BUCKET_NODES - 1) >> NBSHIFT;  // 147 <= MAXNB

  auto align = [](size_t v) { return (v + 255) & ~(size_t)255; };
  char* p = (char*)d_ws;
  float* dinv       = (float*)p; p += align((size_t)N * 4);
  int*   rp         = (int*)p;   p += align((size_t)(N + 1) * 4);
  int*   bucketCur  = (int*)p;   p += align((size_t)MAXNB * 4);
  int*   bucketBase = (int*)p;   p += align((size_t)(MAXNB + 1) * 4);
  int*   col        = (int*)p;   p += align((size_t)E * 4);
  float* hs1        = (float*)p; p += align((size_t)N * 64 * 4);  // bf16 rows use half
  float* hs2        = (float*)p; p += align((size_t)N * 16 * 4);
  // bucketArr (~6 MB) aliases hs1 (19.2 MB region): pass A/B finish before
  // k_gemm64 overwrites it (serial stream).
  int* bucketArr = (int*)hs1;

  const int nbA = (E + CHA - 1) / CHA;
  const int nbWave = ((size_t)N * 64 + 255) / 256;

  kA_zero  <<<(NB + 255) / 256, 256, 0, stream>>>(bucketCur, NB);
  kA_bucket<<<nbA, TA, 0, stream>>>(src, dst, bucketCur, bucketArr, NB, E);
  kB_scan  <<<1, 256, 0, stream>>>(bucketCur, bucketBase, rp, NB, N);
  kB_fill  <<<NB, TB, 0, stream>>>(bucketArr, bucketCur, bucketBase, rp, dinv, col, N);

  k_gemm64  <<<(N + 63) / 64, 256, 0, stream>>>((const float4*)x, (const float4*)W1,
                                                dinv, (uint2*)hs1, N);
  k_agg64_w2<<<nbWave, 256, 0, stream>>>((const uint4*)hs1, rp, col, dinv,
                                         b1, W2, hs2, N);
  k_agg16   <<<nbWave, 256, 0, stream>>>((const float4*)hs2, rp, col, dinv,
                                         b2, (float4*)out, N);
}

// Round 6
// 133.446 us; speedup vs baseline: 1.3727x; 1.3727x over previous
//
#include <hip/hip_runtime.h>

// GCN 2-layer forward on MI355X.
// out = Ahat @ (X W1) -> relu -> Ahat @ (H W2), Ahat = D^-1/2 (A+I) D^-1/2.
// CSR via two-level bucketed counting sort. hs1 stored bf16 (half gather
// traffic). Layer-1 aggregate: R4-proven 4 groups x 16 lanes wave shape,
// uint2 (8B) bf16 loads, 2-edge unrolled inner loop (8 rows in flight per
// wave), fused (h1 @ W2)*dinv epilogue.

#define NBSHIFT 9
#define BUCKET_NODES 512
#define CAP 10240
#define CHA 8192
#define TA 512
#define TB 512
#define MAXNB 160

__device__ __forceinline__ unsigned bfpack(float a, float b) {
  unsigned ua = __float_as_uint(a), ub = __float_as_uint(b);
  ua += 0x7fffu + ((ua >> 16) & 1u);   // RNE to bf16
  ub += 0x7fffu + ((ub >> 16) & 1u);
  return (ua >> 16) | (ub & 0xffff0000u);
}

// ---------------- Pass A: coarse bucketing ----------------
__global__ void kA_zero(int* __restrict__ bucketCur, int NB) {
  int i = blockIdx.x * blockDim.x + threadIdx.x;
  if (i < NB) bucketCur[i] = 0;
}

__launch_bounds__(TA)
__global__ void kA_bucket(const int* __restrict__ src, const int* __restrict__ dst,
                          int* __restrict__ bucketCur, int* __restrict__ bucketArr,
                          int NB, int E) {
  __shared__ int stage[CHA];
  __shared__ unsigned char binOf[CHA];
  __shared__ int cnt[MAXNB];
  __shared__ int off[MAXNB];
  __shared__ int gpos[MAXNB];
  __shared__ int cursor[MAXNB];
  __shared__ int scanbuf[256];
  int t = threadIdx.x;
  int e0 = blockIdx.x * CHA;

  for (int i = t; i < NB; i += TA) cnt[i] = 0;
  __syncthreads();
  for (int i = t; i < CHA; i += TA) {
    int e = e0 + i;
    if (e < E) atomicAdd(&cnt[dst[e] >> NBSHIFT], 1);
  }
  __syncthreads();
  if (t < 256) scanbuf[t] = (t < NB) ? cnt[t] : 0;
  __syncthreads();
  for (int o = 1; o < 256; o <<= 1) {
    int add = (t < 256 && t >= o) ? scanbuf[t - o] : 0;
    __syncthreads();
    if (t < 256) scanbuf[t] += add;
    __syncthreads();
  }
  if (t < NB) {
    off[t] = scanbuf[t] - cnt[t];
    cursor[t] = off[t];
    gpos[t] = (cnt[t] > 0) ? atomicAdd(&bucketCur[t], cnt[t]) : 0;
  }
  __syncthreads();
  for (int i = t; i < CHA; i += TA) {
    int e = e0 + i;
    if (e < E) {
      int d = dst[e], s = src[e];
      int b = d >> NBSHIFT;
      int p = atomicAdd(&cursor[b], 1);
      stage[p] = (s << NBSHIFT) | (d & (BUCKET_NODES - 1));
      binOf[p] = (unsigned char)b;
    }
  }
  __syncthreads();
  int total = scanbuf[255];
  for (int i = t; i < total; i += TA) {
    int b = binOf[i];
    int destIdx = gpos[b] + (i - off[b]);
    if (destIdx < CAP) bucketArr[b * CAP + destIdx] = stage[i];
  }
}

// ---------------- Scan bucket totals ----------------
__global__ void kB_scan(const int* __restrict__ bucketCur, int* __restrict__ bucketBase,
                        int* __restrict__ rp, int NB, int N) {
  __shared__ int s[256];
  int t = threadIdx.x;
  int v = (t < NB) ? min(bucketCur[t], CAP) : 0;
  s[t] = v;
  __syncthreads();
  for (int o = 1; o < 256; o <<= 1) {
    int add = (t >= o) ? s[t - o] : 0;
    __syncthreads();
    s[t] += add;
    __syncthreads();
  }
  if (t < NB) bucketBase[t] = s[t] - v;  // exclusive
  if (t == NB - 1) {
    bucketBase[NB] = s[t];
    rp[N] = s[t];
  }
}

// ---------------- Pass B: per-bucket fine counting sort in LDS ----------------
__launch_bounds__(TB)
__global__ void kB_fill(const int* __restrict__ bucketArr, const int* __restrict__ bucketCur,
                        const int* __restrict__ bucketBase,
                        int* __restrict__ rp, float* __restrict__ dinv,
                        int* __restrict__ col, int N) {
  __shared__ int hist[BUCKET_NODES];
  __shared__ int noff[BUCKET_NODES];
  __shared__ int cur[BUCKET_NODES];
  __shared__ int colStage[CAP];
  int b = blockIdx.x;
  int t = threadIdx.x;
  int nE = min(bucketCur[b], CAP);
  int base = b * CAP;

  hist[t] = 0;
  __syncthreads();
  for (int i = t; i < nE; i += TB) {
    atomicAdd(&hist[bucketArr[base + i] & (BUCKET_NODES - 1)], 1);
  }
  __syncthreads();
  int myv = hist[t];
  noff[t] = myv;
  __syncthreads();
  for (int o = 1; o < BUCKET_NODES; o <<= 1) {
    int add = (t >= o) ? noff[t - o] : 0;
    __syncthreads();
    noff[t] += add;
    __syncthreads();
  }
  int excl = noff[t] - myv;
  cur[t] = excl;
  int gnode = b * BUCKET_NODES + t;
  if (gnode < N) {
    rp[gnode] = bucketBase[b] + excl;
    dinv[gnode] = rsqrtf((float)(myv + 1));  // +1 self loop
  }
  __syncthreads();
  for (int i = t; i < nE; i += TB) {
    int v = bucketArr[base + i];
    int p = atomicAdd(&cur[v & (BUCKET_NODES - 1)], 1);
    colStage[p] = v >> NBSHIFT;
  }
  __syncthreads();
  int gb = bucketBase[b];
  for (int i = t; i < nE; i += TB) col[gb + i] = colStage[i];
}

// ---------------- Dense compute ----------------
// hs1(bf16) = dinv[r] * (X @ W1). Register-tiled 64x64 block, 4x4/thread.
__launch_bounds__(256)
__global__ void k_gemm64(const float4* __restrict__ X4, const float4* __restrict__ W4,
                         const float* __restrict__ dinv, uint2* __restrict__ outb,
                         int n) {
  __shared__ float4 Xs[64 * 17];
  __shared__ float4 Ws[64 * 16];
  int t = threadIdx.x;
  int base = blockIdx.x * 64;
  {
    int rr = t >> 2, q = t & 3;
    int r = base + rr;
    #pragma unroll
    for (int c = 0; c < 4; c++) {
      float4 v = make_float4(0.f, 0.f, 0.f, 0.f);
      if (r < n) v = X4[r * 16 + q * 4 + c];
      Xs[rr * 17 + q * 4 + c] = v;
      Ws[t + 256 * c] = W4[t + 256 * c];
    }
  }
  __syncthreads();

  int tx = t & 15, ty = t >> 4;
  float4 a0 = make_float4(0.f, 0.f, 0.f, 0.f), a1 = a0, a2 = a0, a3 = a0;
  #pragma unroll
  for (int kb = 0; kb < 16; kb++) {
    float4 x0 = Xs[(ty * 4 + 0) * 17 + kb];
    float4 x1 = Xs[(ty * 4 + 1) * 17 + kb];
    float4 x2 = Xs[(ty * 4 + 2) * 17 + kb];
    float4 x3 = Xs[(ty * 4 + 3) * 17 + kb];
    float4 w0 = Ws[(kb * 4 + 0) * 16 + tx];
    float4 w1 = Ws[(kb * 4 + 1) * 16 + tx];
    float4 w2 = Ws[(kb * 4 + 2) * 16 + tx];
    float4 w3 = Ws[(kb * 4 + 3) * 16 + tx];
    #define FMA4(A, XS) \
      A.x = fmaf(XS.x, w0.x, A.x); A.y = fmaf(XS.x, w0.y, A.y); \
      A.z = fmaf(XS.x, w0.z, A.z); A.w = fmaf(XS.x, w0.w, A.w); \
      A.x = fmaf(XS.y, w1.x, A.x); A.y = fmaf(XS.y, w1.y, A.y); \
      A.z = fmaf(XS.y, w1.z, A.z); A.w = fmaf(XS.y, w1.w, A.w); \
      A.x = fmaf(XS.z, w2.x, A.x); A.y = fmaf(XS.z, w2.y, A.y); \
      A.z = fmaf(XS.z, w2.z, A.z); A.w = fmaf(XS.z, w2.w, A.w); \
      A.x = fmaf(XS.w, w3.x, A.x); A.y = fmaf(XS.w, w3.y, A.y); \
      A.z = fmaf(XS.w, w3.z, A.z); A.w = fmaf(XS.w, w3.w, A.w);
    FMA4(a0, x0) FMA4(a1, x1) FMA4(a2, x2) FMA4(a3, x3)
    #undef FMA4
  }
  #pragma unroll
  for (int i = 0; i < 4; i++) {
    int r = base + ty * 4 + i;
    if (r < n) {
      float s = dinv[r];
      float4 a = (i == 0) ? a0 : (i == 1) ? a1 : (i == 2) ? a2 : a3;
      uint2 pk;
      pk.x = bfpack(a.x * s, a.y * s);
      pk.y = bfpack(a.z * s, a.w * s);
      outb[r * 16 + tx] = pk;   // row stride 16 uint2 = 128 B
    }
  }
}

// Layer-1 aggregate + relu + fused (h1 @ W2)*dinv epilogue.
// R4 wave shape: 4 groups x 16 lanes; lane c covers bf16 cols 4c..4c+3 via
// one uint2 (8 B). 2-edge unrolled loop: two independent row loads in
// flight per group per iteration.
__launch_bounds__(256)
__global__ void k_agg64_w2(const uint2* __restrict__ hsb,    // [n*16] bf16 rows
                           const int* __restrict__ rp,
                           const int* __restrict__ col,
                           const float* __restrict__ dinv,
                           const float* __restrict__ b1,
                           const float* __restrict__ W2,     // 64x16
                           float* __restrict__ hs2,          // [n*16] f32
                           int n) {
  int lane = threadIdx.x & 63;
  int c = lane & 15;     // cols 4c..4c+3
  int sub = lane >> 4;   // group 0..3
  int node = (blockIdx.x * blockDim.x + threadIdx.x) >> 6;
  if (node >= n) return;

  float4 b14 = ((const float4*)b1)[c];
  float w2r[16];
  #pragma unroll
  for (int i = 0; i < 16; i++) w2r[i] = W2[(sub * 16 + i) * 16 + c];

  int s0 = rp[node], s1 = rp[node + 1];
  int dt = s1 - s0 + 1;  // virtual edge list: [self] + col[s0..s1)
  float ax = 0.f, ay = 0.f, az = 0.f, aw = 0.f;
  int t = sub;
  int idx0 = 0, idx1 = 0;
  if (t < dt)     idx0 = (t == 0) ? node : col[s0 + t - 1];
  if (t + 4 < dt) idx1 = col[s0 + t + 3];
  while (t < dt) {
    int cur0 = idx0, cur1 = idx1;
    bool has1 = (t + 4) < dt;
    int tn = t + 8;
    if (tn < dt)     idx0 = col[s0 + tn - 1];
    if (tn + 4 < dt) idx1 = col[s0 + tn + 3];
    uint2 u0 = hsb[cur0 * 16 + c];
    if (has1) {
      uint2 u1 = hsb[cur1 * 16 + c];
      ax += __uint_as_float(u1.x << 16);
      ay += __uint_as_float(u1.x & 0xffff0000u);
      az += __uint_as_float(u1.y << 16);
      aw += __uint_as_float(u1.y & 0xffff0000u);
    }
    ax += __uint_as_float(u0.x << 16);
    ay += __uint_as_float(u0.x & 0xffff0000u);
    az += __uint_as_float(u0.y << 16);
    aw += __uint_as_float(u0.y & 0xffff0000u);
    t = tn;
  }
  #pragma unroll
  for (int m = 16; m <= 32; m <<= 1) {
    ax += __shfl_xor(ax, m);
    ay += __shfl_xor(ay, m);
    az += __shfl_xor(az, m);
    aw += __shfl_xor(aw, m);
  }
  float dv = dinv[node];
  float hx = fmaxf(ax * dv + b14.x, 0.f);
  float hy = fmaxf(ay * dv + b14.y, 0.f);
  float hz = fmaxf(az * dv + b14.z, 0.f);
  float hw = fmaxf(aw * dv + b14.w, 0.f);

  float part = 0.f;
  #pragma unroll
  for (int i = 0; i < 16; i++) {
    int srcLane = 4 * sub + (i >> 2);
    float h;
    if ((i & 3) == 0)      h = __shfl(hx, srcLane);
    else if ((i & 3) == 1) h = __shfl(hy, srcLane);
    else if ((i & 3) == 2) h = __shfl(hz, srcLane);
    else                   h = __shfl(hw, srcLane);
    part = fmaf(h, w2r[i], part);
  }
  #pragma unroll
  for (int m = 16; m <= 32; m <<= 1) part += __shfl_xor(part, m);
  if (sub == 0) hs2[node * 16 + c] = part * dv;
}

// Layer-2 aggregate: one wave per node, 16 groups x 4 lanes. Final output.
__launch_bounds__(256)
__global__ void k_agg16(const float4* __restrict__ hs2_4,  // [n*4]
                        const int* __restrict__ rp,
                        const int* __restrict__ col,
                        const float* __restrict__ dinv,
                        const float* __restrict__ b2,
                        float4* __restrict__ out4,          // [n*4]
                        int n) {
  int lane = threadIdx.x & 63;
  int c = lane & 3;
  int sub = lane >> 2;
  int node = (blockIdx.x * blockDim.x + threadIdx.x) >> 6;
  if (node >= n) return;

  int s0 = rp[node], s1 = rp[node + 1];
  int dt = s1 - s0 + 1;
  float ax = 0.f, ay = 0.f, az = 0.f, aw = 0.f;
  int t = sub;
  int idx = 0;
  if (t < dt) idx = (t == 0) ? node : col[s0 + t - 1];
  while (t < dt) {
    int curi = idx;
    int tn = t + 16;
    if (tn < dt) idx = col[s0 + tn - 1];
    float4 row = hs2_4[curi * 4 + c];
    ax += row.x; ay += row.y; az += row.z; aw += row.w;
    t = tn;
  }
  #pragma unroll
  for (int m = 4; m <= 32; m <<= 1) {
    ax += __shfl_xor(ax, m);
    ay += __shfl_xor(ay, m);
    az += __shfl_xor(az, m);
    aw += __shfl_xor(aw, m);
  }
  if (sub == 0) {
    float dv = dinv[node];
    float4 b24 = ((const float4*)b2)[c];
    float4 o;
    o.x = ax * dv + b24.x;
    o.y = ay * dv + b24.y;
    o.z = az * dv + b24.z;
    o.w = aw * dv + b24.w;
    out4[node * 4 + c] = o;
  }
}

extern "C" void kernel_launch(void* const* d_in, const int* in_sizes, int n_in,
                              void* d_out, int out_size, void* d_ws, size_t ws_size,
                              hipStream_t stream) {
  const float* x  = (const float*)d_in[0];
  const int* edges = (const int*)d_in[1];
  const float* W1 = (const float*)d_in[2];
  const float* b1 = (const float*)d_in[3];
  const float* W2 = (const float*)d_in[4];
  const float* b2 = (const float*)d_in[5];
  float* out = (float*)d_out;

  const int N = in_sizes[0] / 64;
  const int E = in_sizes[1] / 2;
  const int* src = edges;
  const int* dst = edges + E;
  const int NB = (N + BUCKET_NODES - 1) >> NBSHIFT;  // 147 <= MAXNB

  auto align = [](size_t v) { return (v + 255) & ~(size_t)255; };
  char* p = (char*)d_ws;
  float* dinv       = (float*)p; p += align((size_t)N * 4);
  int*   rp         = (int*)p;   p += align((size_t)(N + 1) * 4);
  int*   bucketCur  = (int*)p;   p += align((size_t)MAXNB * 4);
  int*   bucketBase = (int*)p;   p += align((size_t)(MAXNB + 1) * 4);
  int*   col        = (int*)p;   p += align((size_t)E * 4);
  float* hs1        = (float*)p; p += align((size_t)N * 64 * 4);  // bf16 rows use half
  float* hs2        = (float*)p; p += align((size_t)N * 16 * 4);
  // bucketArr (~6 MB) aliases hs1 region: pass A/B finish before k_gemm64
  // overwrites it (serial stream).
  int* bucketArr = (int*)hs1;

  const int nbA = (E + CHA - 1) / CHA;
  const int nbWave = ((size_t)N * 64 + 255) / 256;

  kA_zero  <<<(NB + 255) / 256, 256, 0, stream>>>(bucketCur, NB);
  kA_bucket<<<nbA, TA, 0, stream>>>(src, dst, bucketCur, bucketArr, NB, E);
  kB_scan  <<<1, 256, 0, stream>>>(bucketCur, bucketBase, rp, NB, N);
  kB_fill  <<<NB, TB, 0, stream>>>(bucketArr, bucketCur, bucketBase, rp, dinv, col, N);

  k_gemm64  <<<(N + 63) / 64, 256, 0, stream>>>((const float4*)x, (const float4*)W1,
                                                dinv, (uint2*)hs1, N);
  k_agg64_w2<<<nbWave, 256, 0, stream>>>((const uint2*)hs1, rp, col, dinv,
                                         b1, W2, hs2, N);
  k_agg16   <<<nbWave, 256, 0, stream>>>((const float4*)hs2, rp, col, dinv,
                                         b2, (float4*)out, N);
}

// Round 7
// 129.754 us; speedup vs baseline: 1.4118x; 1.0285x over previous
//
#include <hip/hip_runtime.h>

// GCN 2-layer forward on MI355X.
// out = Ahat @ (X W1) -> relu -> Ahat @ (H W2), Ahat = D^-1/2 (A+I) D^-1/2.
// CSR via two-level bucketed counting sort. hs1 AND hs2 stored bf16 (half
// gather traffic; hs2 table 2.4 MB -> L2-resident). Aggregates use the
// R4-proven "few groups x 16-wide row segments" wave shape with deep
// unrolling for memory-level parallelism. Layer-2 GEMM fused into the
// layer-1 aggregate epilogue.

#define NBSHIFT 9
#define BUCKET_NODES 512
#define CAP 10240
#define CHA 8192
#define TA 512
#define TB 512
#define MAXNB 160

__device__ __forceinline__ unsigned bfpack(float a, float b) {
  unsigned ua = __float_as_uint(a), ub = __float_as_uint(b);
  ua += 0x7fffu + ((ua >> 16) & 1u);   // RNE to bf16
  ub += 0x7fffu + ((ub >> 16) & 1u);
  return (ua >> 16) | (ub & 0xffff0000u);
}

// ---------------- Pass A: coarse bucketing ----------------
__launch_bounds__(TA)
__global__ void kA_bucket(const int* __restrict__ src, const int* __restrict__ dst,
                          int* __restrict__ bucketCur, int* __restrict__ bucketArr,
                          int NB, int E) {
  __shared__ int stage[CHA];
  __shared__ unsigned char binOf[CHA];
  __shared__ int cnt[MAXNB];
  __shared__ int off[MAXNB];
  __shared__ int gpos[MAXNB];
  __shared__ int cursor[MAXNB];
  __shared__ int scanbuf[256];
  int t = threadIdx.x;
  int e0 = blockIdx.x * CHA;

  for (int i = t; i < NB; i += TA) cnt[i] = 0;
  __syncthreads();
  for (int i = t; i < CHA; i += TA) {
    int e = e0 + i;
    if (e < E) atomicAdd(&cnt[dst[e] >> NBSHIFT], 1);
  }
  __syncthreads();
  if (t < 256) scanbuf[t] = (t < NB) ? cnt[t] : 0;
  __syncthreads();
  for (int o = 1; o < 256; o <<= 1) {
    int add = (t < 256 && t >= o) ? scanbuf[t - o] : 0;
    __syncthreads();
    if (t < 256) scanbuf[t] += add;
    __syncthreads();
  }
  if (t < NB) {
    off[t] = scanbuf[t] - cnt[t];
    cursor[t] = off[t];
    gpos[t] = (cnt[t] > 0) ? atomicAdd(&bucketCur[t], cnt[t]) : 0;
  }
  __syncthreads();
  for (int i = t; i < CHA; i += TA) {
    int e = e0 + i;
    if (e < E) {
      int d = dst[e], s = src[e];
      int b = d >> NBSHIFT;
      int p = atomicAdd(&cursor[b], 1);
      stage[p] = (s << NBSHIFT) | (d & (BUCKET_NODES - 1));
      binOf[p] = (unsigned char)b;
    }
  }
  __syncthreads();
  int total = scanbuf[255];
  for (int i = t; i < total; i += TA) {
    int b = binOf[i];
    int destIdx = gpos[b] + (i - off[b]);
    if (destIdx < CAP) bucketArr[b * CAP + destIdx] = stage[i];
  }
}

// ---------------- Scan bucket totals ----------------
__global__ void kB_scan(const int* __restrict__ bucketCur, int* __restrict__ bucketBase,
                        int* __restrict__ rp, int NB, int N) {
  __shared__ int s[256];
  int t = threadIdx.x;
  int v = (t < NB) ? min(bucketCur[t], CAP) : 0;
  s[t] = v;
  __syncthreads();
  for (int o = 1; o < 256; o <<= 1) {
    int add = (t >= o) ? s[t - o] : 0;
    __syncthreads();
    s[t] += add;
    __syncthreads();
  }
  if (t < NB) bucketBase[t] = s[t] - v;  // exclusive
  if (t == NB - 1) {
    bucketBase[NB] = s[t];
    rp[N] = s[t];
  }
}

// ---------------- Pass B: per-bucket fine counting sort in LDS ----------------
__launch_bounds__(TB)
__global__ void kB_fill(const int* __restrict__ bucketArr, const int* __restrict__ bucketCur,
                        const int* __restrict__ bucketBase,
                        int* __restrict__ rp, float* __restrict__ dinv,
                        int* __restrict__ col, int N) {
  __shared__ int hist[BUCKET_NODES];
  __shared__ int noff[BUCKET_NODES];
  __shared__ int cur[BUCKET_NODES];
  __shared__ int colStage[CAP];
  int b = blockIdx.x;
  int t = threadIdx.x;
  int nE = min(bucketCur[b], CAP);
  int base = b * CAP;

  hist[t] = 0;
  __syncthreads();
  for (int i = t; i < nE; i += TB) {
    atomicAdd(&hist[bucketArr[base + i] & (BUCKET_NODES - 1)], 1);
  }
  __syncthreads();
  int myv = hist[t];
  noff[t] = myv;
  __syncthreads();
  for (int o = 1; o < BUCKET_NODES; o <<= 1) {
    int add = (t >= o) ? noff[t - o] : 0;
    __syncthreads();
    noff[t] += add;
    __syncthreads();
  }
  int excl = noff[t] - myv;
  cur[t] = excl;
  int gnode = b * BUCKET_NODES + t;
  if (gnode < N) {
    rp[gnode] = bucketBase[b] + excl;
    dinv[gnode] = rsqrtf((float)(myv + 1));  // +1 self loop
  }
  __syncthreads();
  for (int i = t; i < nE; i += TB) {
    int v = bucketArr[base + i];
    int p = atomicAdd(&cur[v & (BUCKET_NODES - 1)], 1);
    colStage[p] = v >> NBSHIFT;
  }
  __syncthreads();
  int gb = bucketBase[b];
  for (int i = t; i < nE; i += TB) col[gb + i] = colStage[i];
}

// ---------------- Dense compute ----------------
// hs1(bf16) = dinv[r] * (X @ W1). Register-tiled 64x64 block, 4x4/thread.
__launch_bounds__(256)
__global__ void k_gemm64(const float4* __restrict__ X4, const float4* __restrict__ W4,
                         const float* __restrict__ dinv, uint2* __restrict__ outb,
                         int n) {
  __shared__ float4 Xs[64 * 17];
  __shared__ float4 Ws[64 * 16];
  int t = threadIdx.x;
  int base = blockIdx.x * 64;
  {
    int rr = t >> 2, q = t & 3;
    int r = base + rr;
    #pragma unroll
    for (int c = 0; c < 4; c++) {
      float4 v = make_float4(0.f, 0.f, 0.f, 0.f);
      if (r < n) v = X4[r * 16 + q * 4 + c];
      Xs[rr * 17 + q * 4 + c] = v;
      Ws[t + 256 * c] = W4[t + 256 * c];
    }
  }
  __syncthreads();

  int tx = t & 15, ty = t >> 4;
  float4 a0 = make_float4(0.f, 0.f, 0.f, 0.f), a1 = a0, a2 = a0, a3 = a0;
  #pragma unroll
  for (int kb = 0; kb < 16; kb++) {
    float4 x0 = Xs[(ty * 4 + 0) * 17 + kb];
    float4 x1 = Xs[(ty * 4 + 1) * 17 + kb];
    float4 x2 = Xs[(ty * 4 + 2) * 17 + kb];
    float4 x3 = Xs[(ty * 4 + 3) * 17 + kb];
    float4 w0 = Ws[(kb * 4 + 0) * 16 + tx];
    float4 w1 = Ws[(kb * 4 + 1) * 16 + tx];
    float4 w2 = Ws[(kb * 4 + 2) * 16 + tx];
    float4 w3 = Ws[(kb * 4 + 3) * 16 + tx];
    #define FMA4(A, XS) \
      A.x = fmaf(XS.x, w0.x, A.x); A.y = fmaf(XS.x, w0.y, A.y); \
      A.z = fmaf(XS.x, w0.z, A.z); A.w = fmaf(XS.x, w0.w, A.w); \
      A.x = fmaf(XS.y, w1.x, A.x); A.y = fmaf(XS.y, w1.y, A.y); \
      A.z = fmaf(XS.y, w1.z, A.z); A.w = fmaf(XS.y, w1.w, A.w); \
      A.x = fmaf(XS.z, w2.x, A.x); A.y = fmaf(XS.z, w2.y, A.y); \
      A.z = fmaf(XS.z, w2.z, A.z); A.w = fmaf(XS.z, w2.w, A.w); \
      A.x = fmaf(XS.w, w3.x, A.x); A.y = fmaf(XS.w, w3.y, A.y); \
      A.z = fmaf(XS.w, w3.z, A.z); A.w = fmaf(XS.w, w3.w, A.w);
    FMA4(a0, x0) FMA4(a1, x1) FMA4(a2, x2) FMA4(a3, x3)
    #undef FMA4
  }
  #pragma unroll
  for (int i = 0; i < 4; i++) {
    int r = base + ty * 4 + i;
    if (r < n) {
      float s = dinv[r];
      float4 a = (i == 0) ? a0 : (i == 1) ? a1 : (i == 2) ? a2 : a3;
      uint2 pk;
      pk.x = bfpack(a.x * s, a.y * s);
      pk.y = bfpack(a.z * s, a.w * s);
      outb[r * 16 + tx] = pk;   // row stride 16 uint2 = 128 B
    }
  }
}

// Layer-1 aggregate + relu + fused (h1 @ W2)*dinv epilogue. 4 groups x 16
// lanes; lane c covers bf16 cols 4c..4c+3 (uint2, 8 B). 4-edge unrolled
// inner loop: 16 independent row loads in flight per wave.
__launch_bounds__(256)
__global__ void k_agg64_w2(const uint2* __restrict__ hsb,    // [n*16] bf16 rows
                           const int* __restrict__ rp,
                           const int* __restrict__ col,
                           const float* __restrict__ dinv,
                           const float* __restrict__ b1,
                           const float* __restrict__ W2,     // 64x16
                           unsigned* __restrict__ hs2b,      // [n*8] bf16 rows
                           int n) {
  int lane = threadIdx.x & 63;
  int c = lane & 15;     // cols 4c..4c+3
  int sub = lane >> 4;   // group 0..3
  int node = (blockIdx.x * blockDim.x + threadIdx.x) >> 6;
  if (node >= n) return;

  float4 b14 = ((const float4*)b1)[c];
  float w2r[16];
  #pragma unroll
  for (int i = 0; i < 16; i++) w2r[i] = W2[(sub * 16 + i) * 16 + c];

  int s0 = rp[node], s1 = rp[node + 1];
  int dt = s1 - s0 + 1;  // virtual edge list: [self] + col[s0..s1)
  float ax = 0.f, ay = 0.f, az = 0.f, aw = 0.f;
  int t = sub;
  int i0 = 0, i1 = 0, i2 = 0, i3 = 0;
  if (t < dt)      i0 = (t == 0) ? node : col[s0 + t - 1];
  if (t + 4 < dt)  i1 = col[s0 + t + 3];
  if (t + 8 < dt)  i2 = col[s0 + t + 7];
  if (t + 12 < dt) i3 = col[s0 + t + 11];
  while (t < dt) {
    int c0 = i0, c1 = i1, c2 = i2, c3 = i3;
    bool h1 = (t + 4) < dt, h2 = (t + 8) < dt, h3 = (t + 12) < dt;
    int tn = t + 16;
    if (tn < dt)      i0 = col[s0 + tn - 1];
    if (tn + 4 < dt)  i1 = col[s0 + tn + 3];
    if (tn + 8 < dt)  i2 = col[s0 + tn + 7];
    if (tn + 12 < dt) i3 = col[s0 + tn + 11];
    uint2 u0 = hsb[c0 * 16 + c];
    uint2 u1 = h1 ? hsb[c1 * 16 + c] : make_uint2(0u, 0u);
    uint2 u2 = h2 ? hsb[c2 * 16 + c] : make_uint2(0u, 0u);
    uint2 u3 = h3 ? hsb[c3 * 16 + c] : make_uint2(0u, 0u);
    ax += __uint_as_float(u0.x << 16) + __uint_as_float(u1.x << 16)
        + __uint_as_float(u2.x << 16) + __uint_as_float(u3.x << 16);
    ay += __uint_as_float(u0.x & 0xffff0000u) + __uint_as_float(u1.x & 0xffff0000u)
        + __uint_as_float(u2.x & 0xffff0000u) + __uint_as_float(u3.x & 0xffff0000u);
    az += __uint_as_float(u0.y << 16) + __uint_as_float(u1.y << 16)
        + __uint_as_float(u2.y << 16) + __uint_as_float(u3.y << 16);
    aw += __uint_as_float(u0.y & 0xffff0000u) + __uint_as_float(u1.y & 0xffff0000u)
        + __uint_as_float(u2.y & 0xffff0000u) + __uint_as_float(u3.y & 0xffff0000u);
    t = tn;
  }
  #pragma unroll
  for (int m = 16; m <= 32; m <<= 1) {
    ax += __shfl_xor(ax, m);
    ay += __shfl_xor(ay, m);
    az += __shfl_xor(az, m);
    aw += __shfl_xor(aw, m);
  }
  float dv = dinv[node];
  float hx = fmaxf(ax * dv + b14.x, 0.f);
  float hy = fmaxf(ay * dv + b14.y, 0.f);
  float hz = fmaxf(az * dv + b14.z, 0.f);
  float hw = fmaxf(aw * dv + b14.w, 0.f);

  float part = 0.f;
  #pragma unroll
  for (int i = 0; i < 16; i++) {
    int srcLane = 4 * sub + (i >> 2);
    float h;
    if ((i & 3) == 0)      h = __shfl(hx, srcLane);
    else if ((i & 3) == 1) h = __shfl(hy, srcLane);
    else if ((i & 3) == 2) h = __shfl(hz, srcLane);
    else                   h = __shfl(hw, srcLane);
    part = fmaf(h, w2r[i], part);
  }
  #pragma unroll
  for (int m = 16; m <= 32; m <<= 1) part += __shfl_xor(part, m);
  part *= dv;
  // pack pairs of adjacent output cols to bf16; even-c lanes of group 0 write
  float pnext = __shfl_down(part, 1);
  if (sub == 0 && (c & 1) == 0) {
    hs2b[node * 8 + (c >> 1)] = bfpack(part, pnext);
  }
}

// Layer-2 aggregate: one wave per node, 16 groups x 4 lanes; uint2 bf16
// loads (row = 32 B), 2-edge unroll -> 32 rows in flight. Final output f32.
__launch_bounds__(256)
__global__ void k_agg16(const uint2* __restrict__ hs2b,    // [n*4] bf16 rows
                        const int* __restrict__ rp,
                        const int* __restrict__ col,
                        const float* __restrict__ dinv,
                        const float* __restrict__ b2,
                        float4* __restrict__ out4,          // [n*4]
                        int n) {
  int lane = threadIdx.x & 63;
  int c = lane & 3;      // cols 4c..4c+3
  int sub = lane >> 2;   // group 0..15
  int node = (blockIdx.x * blockDim.x + threadIdx.x) >> 6;
  if (node >= n) return;

  int s0 = rp[node], s1 = rp[node + 1];
  int dt = s1 - s0 + 1;
  float ax = 0.f, ay = 0.f, az = 0.f, aw = 0.f;
  int t = sub;
  int i0 = 0, i1 = 0;
  if (t < dt)      i0 = (t == 0) ? node : col[s0 + t - 1];
  if (t + 16 < dt) i1 = col[s0 + t + 15];
  while (t < dt) {
    int c0 = i0, c1 = i1;
    bool h1 = (t + 16) < dt;
    int tn = t + 32;
    if (tn < dt)      i0 = col[s0 + tn - 1];
    if (tn + 16 < dt) i1 = col[s0 + tn + 15];
    uint2 u0 = hs2b[c0 * 4 + c];
    uint2 u1 = h1 ? hs2b[c1 * 4 + c] : make_uint2(0u, 0u);
    ax += __uint_as_float(u0.x << 16) + __uint_as_float(u1.x << 16);
    ay += __uint_as_float(u0.x & 0xffff0000u) + __uint_as_float(u1.x & 0xffff0000u);
    az += __uint_as_float(u0.y << 16) + __uint_as_float(u1.y << 16);
    aw += __uint_as_float(u0.y & 0xffff0000u) + __uint_as_float(u1.y & 0xffff0000u);
    t = tn;
  }
  #pragma unroll
  for (int m = 4; m <= 32; m <<= 1) {
    ax += __shfl_xor(ax, m);
    ay += __shfl_xor(ay, m);
    az += __shfl_xor(az, m);
    aw += __shfl_xor(aw, m);
  }
  if (sub == 0) {
    float dv = dinv[node];
    float4 b24 = ((const float4*)b2)[c];
    float4 o;
    o.x = ax * dv + b24.x;
    o.y = ay * dv + b24.y;
    o.z = az * dv + b24.z;
    o.w = aw * dv + b24.w;
    out4[node * 4 + c] = o;
  }
}

extern "C" void kernel_launch(void* const* d_in, const int* in_sizes, int n_in,
                              void* d_out, int out_size, void* d_ws, size_t ws_size,
                              hipStream_t stream) {
  const float* x  = (const float*)d_in[0];
  const int* edges = (const int*)d_in[1];
  const float* W1 = (const float*)d_in[2];
  const float* b1 = (const float*)d_in[3];
  const float* W2 = (const float*)d_in[4];
  const float* b2 = (const float*)d_in[5];
  float* out = (float*)d_out;

  const int N = in_sizes[0] / 64;
  const int E = in_sizes[1] / 2;
  const int* src = edges;
  const int* dst = edges + E;
  const int NB = (N + BUCKET_NODES - 1) >> NBSHIFT;  // 147 <= MAXNB

  auto align = [](size_t v) { return (v + 255) & ~(size_t)255; };
  char* p = (char*)d_ws;
  float* dinv       = (float*)p; p += align((size_t)N * 4);
  int*   rp         = (int*)p;   p += align((size_t)(N + 1) * 4);
  int*   bucketCur  = (int*)p;   p += align((size_t)MAXNB * 4);
  int*   bucketBase = (int*)p;   p += align((size_t)(MAXNB + 1) * 4);
  int*   col        = (int*)p;   p += align((size_t)E * 4);
  float* hs1        = (float*)p; p += align((size_t)N * 64 * 4);  // bf16 rows use half
  float* hs2        = (float*)p; p += align((size_t)N * 16 * 4);  // bf16 rows use half
  // bucketArr (~6 MB) aliases hs1 region: pass A/B finish before k_gemm64
  // overwrites it (serial stream).
  int* bucketArr = (int*)hs1;

  const int nbA = (E + CHA - 1) / CHA;
  const int nbWave = ((size_t)N * 64 + 255) / 256;

  hipMemsetAsync(bucketCur, 0, (size_t)MAXNB * 4, stream);
  kA_bucket<<<nbA, TA, 0, stream>>>(src, dst, bucketCur, bucketArr, NB, E);
  kB_scan  <<<1, 256, 0, stream>>>(bucketCur, bucketBase, rp, NB, N);
  kB_fill  <<<NB, TB, 0, stream>>>(bucketArr, bucketCur, bucketBase, rp, dinv, col, N);

  k_gemm64  <<<(N + 63) / 64, 256, 0, stream>>>((const float4*)x, (const float4*)W1,
                                                dinv, (uint2*)hs1, N);
  k_agg64_w2<<<nbWave, 256, 0, stream>>>((const uint2*)hs1, rp, col, dinv,
                                         b1, W2, (unsigned*)hs2, N);
  k_agg16   <<<nbWave, 256, 0, stream>>>((const uint2*)hs2, rp, col, dinv,
                                         b2, (float4*)out, N);
}

// Round 8
// 128.719 us; speedup vs baseline: 1.4231x; 1.0080x over previous
//
#include <hip/hip_runtime.h>

// GCN 2-layer forward on MI355X.
// out = Ahat @ (X W1) -> relu -> Ahat @ (H W2), Ahat = D^-1/2 (A+I) D^-1/2.
// CSR via two-level bucketed counting sort. hs1 AND hs2 stored bf16.
// Aggregates: "few groups x 16B-segment" wave shape, deep unroll for MLP,
// layer-2 GEMM fused into layer-1 aggregate epilogue.
// R7: kB_scan merged into kB_fill (per-block serial base sum); kB_fill uses
// wave-shuffle scan + direct scattered col writes (no 40KB colStage);
// kA caches dst in registers (one global read instead of two).

#define NBSHIFT 9
#define BUCKET_NODES 512
#define CAP 10240
#define CHA 8192
#define TA 512
#define TB 512
#define MAXNB 160
#define EPT 16   // edges per thread in kA (CHA/TA)

__device__ __forceinline__ unsigned bfpack(float a, float b) {
  unsigned ua = __float_as_uint(a), ub = __float_as_uint(b);
  ua += 0x7fffu + ((ua >> 16) & 1u);   // RNE to bf16
  ub += 0x7fffu + ((ub >> 16) & 1u);
  return (ua >> 16) | (ub & 0xffff0000u);
}

// ---------------- Pass A: coarse bucketing ----------------
__launch_bounds__(TA)
__global__ void kA_bucket(const int* __restrict__ src, const int* __restrict__ dst,
                          int* __restrict__ bucketCur, int* __restrict__ bucketArr,
                          int NB, int E) {
  __shared__ int stage[CHA];
  __shared__ unsigned char binOf[CHA];
  __shared__ int cnt[MAXNB];
  __shared__ int off[MAXNB];
  __shared__ int gpos[MAXNB];
  __shared__ int cursor[MAXNB];
  __shared__ int scanbuf[256];
  int t = threadIdx.x;
  int e0 = blockIdx.x * CHA;

  for (int i = t; i < NB; i += TA) cnt[i] = 0;
  __syncthreads();
  int dreg[EPT];
  #pragma unroll
  for (int j = 0; j < EPT; j++) {
    int e = e0 + t + j * TA;
    dreg[j] = (e < E) ? dst[e] : -1;
    if (dreg[j] >= 0) atomicAdd(&cnt[dreg[j] >> NBSHIFT], 1);
  }
  __syncthreads();
  if (t < 256) scanbuf[t] = (t < NB) ? cnt[t] : 0;
  __syncthreads();
  for (int o = 1; o < 256; o <<= 1) {
    int add = (t < 256 && t >= o) ? scanbuf[t - o] : 0;
    __syncthreads();
    if (t < 256) scanbuf[t] += add;
    __syncthreads();
  }
  if (t < NB) {
    off[t] = scanbuf[t] - cnt[t];
    cursor[t] = off[t];
    gpos[t] = (cnt[t] > 0) ? atomicAdd(&bucketCur[t], cnt[t]) : 0;
  }
  __syncthreads();
  #pragma unroll
  for (int j = 0; j < EPT; j++) {
    int e = e0 + t + j * TA;
    if (dreg[j] >= 0) {
      int d = dreg[j], s = src[e];
      int b = d >> NBSHIFT;
      int p = atomicAdd(&cursor[b], 1);
      stage[p] = (s << NBSHIFT) | (d & (BUCKET_NODES - 1));
      binOf[p] = (unsigned char)b;
    }
  }
  __syncthreads();
  int total = scanbuf[255];
  for (int i = t; i < total; i += TA) {
    int b = binOf[i];
    int destIdx = gpos[b] + (i - off[b]);
    if (destIdx < CAP) bucketArr[b * CAP + destIdx] = stage[i];
  }
}

// ---------------- Pass B: per-bucket fine counting sort ----------------
// Computes its own global base (serial sum over <=NB bucket counts), builds
// the per-node histogram, wave-shuffle scan, writes rp/dinv, then scatters
// col directly to global (4B writes confined to a 32KB window -> L2).
__launch_bounds__(TB)
__global__ void kB_fill(const int* __restrict__ bucketArr, const int* __restrict__ bucketCur,
                        int* __restrict__ rp, float* __restrict__ dinv,
                        int* __restrict__ col, int N, int NB) {
  __shared__ int cnts[MAXNB];
  __shared__ int hist[BUCKET_NODES];
  __shared__ int cur[BUCKET_NODES];
  __shared__ int wsum[8], woff[8];
  __shared__ int s_base;
  int b = blockIdx.x;
  int t = threadIdx.x;
  int nE = min(bucketCur[b], CAP);
  int base = b * CAP;

  if (t < NB) cnts[t] = min(bucketCur[t], CAP);
  hist[t] = 0;
  __syncthreads();
  for (int i = t; i < nE; i += TB)
    atomicAdd(&hist[bucketArr[base + i] & (BUCKET_NODES - 1)], 1);
  __syncthreads();
  int myv = hist[t];
  int lane = t & 63, w = t >> 6;
  int incl = myv;
  #pragma unroll
  for (int o = 1; o < 64; o <<= 1) {
    int v = __shfl_up(incl, o);
    if (lane >= o) incl += v;
  }
  if (lane == 63) wsum[w] = incl;
  __syncthreads();
  if (t == 0) {
    int acc = 0;
    for (int i = 0; i < b; i++) acc += cnts[i];
    s_base = acc;
    int a2 = 0;
    #pragma unroll
    for (int i = 0; i < 8; i++) { woff[i] = a2; a2 += wsum[i]; }
    if (b == NB - 1) rp[N] = acc + nE;
  }
  __syncthreads();
  int gexcl = s_base + woff[w] + (incl - myv);
  cur[t] = gexcl;
  int gnode = b * BUCKET_NODES + t;
  if (gnode < N) {
    rp[gnode] = gexcl;
    dinv[gnode] = rsqrtf((float)(myv + 1));  // +1 self loop
  }
  __syncthreads();
  for (int i = t; i < nE; i += TB) {
    int v = bucketArr[base + i];
    int p = atomicAdd(&cur[v & (BUCKET_NODES - 1)], 1);
    col[p] = v >> NBSHIFT;
  }
}

// ---------------- Dense compute ----------------
// hs1(bf16) = dinv[r] * (X @ W1). Register-tiled 64x64 block, 4x4/thread.
__launch_bounds__(256)
__global__ void k_gemm64(const float4* __restrict__ X4, const float4* __restrict__ W4,
                         const float* __restrict__ dinv, uint2* __restrict__ outb,
                         int n) {
  __shared__ float4 Xs[64 * 17];
  __shared__ float4 Ws[64 * 16];
  int t = threadIdx.x;
  int base = blockIdx.x * 64;
  {
    int rr = t >> 2, q = t & 3;
    int r = base + rr;
    #pragma unroll
    for (int c = 0; c < 4; c++) {
      float4 v = make_float4(0.f, 0.f, 0.f, 0.f);
      if (r < n) v = X4[r * 16 + q * 4 + c];
      Xs[rr * 17 + q * 4 + c] = v;
      Ws[t + 256 * c] = W4[t + 256 * c];
    }
  }
  __syncthreads();

  int tx = t & 15, ty = t >> 4;
  float4 a0 = make_float4(0.f, 0.f, 0.f, 0.f), a1 = a0, a2 = a0, a3 = a0;
  #pragma unroll
  for (int kb = 0; kb < 16; kb++) {
    float4 x0 = Xs[(ty * 4 + 0) * 17 + kb];
    float4 x1 = Xs[(ty * 4 + 1) * 17 + kb];
    float4 x2 = Xs[(ty * 4 + 2) * 17 + kb];
    float4 x3 = Xs[(ty * 4 + 3) * 17 + kb];
    float4 w0 = Ws[(kb * 4 + 0) * 16 + tx];
    float4 w1 = Ws[(kb * 4 + 1) * 16 + tx];
    float4 w2 = Ws[(kb * 4 + 2) * 16 + tx];
    float4 w3 = Ws[(kb * 4 + 3) * 16 + tx];
    #define FMA4(A, XS) \
      A.x = fmaf(XS.x, w0.x, A.x); A.y = fmaf(XS.x, w0.y, A.y); \
      A.z = fmaf(XS.x, w0.z, A.z); A.w = fmaf(XS.x, w0.w, A.w); \
      A.x = fmaf(XS.y, w1.x, A.x); A.y = fmaf(XS.y, w1.y, A.y); \
      A.z = fmaf(XS.y, w1.z, A.z); A.w = fmaf(XS.y, w1.w, A.w); \
      A.x = fmaf(XS.z, w2.x, A.x); A.y = fmaf(XS.z, w2.y, A.y); \
      A.z = fmaf(XS.z, w2.z, A.z); A.w = fmaf(XS.z, w2.w, A.w); \
      A.x = fmaf(XS.w, w3.x, A.x); A.y = fmaf(XS.w, w3.y, A.y); \
      A.z = fmaf(XS.w, w3.z, A.z); A.w = fmaf(XS.w, w3.w, A.w);
    FMA4(a0, x0) FMA4(a1, x1) FMA4(a2, x2) FMA4(a3, x3)
    #undef FMA4
  }
  #pragma unroll
  for (int i = 0; i < 4; i++) {
    int r = base + ty * 4 + i;
    if (r < n) {
      float s = dinv[r];
      float4 a = (i == 0) ? a0 : (i == 1) ? a1 : (i == 2) ? a2 : a3;
      uint2 pk;
      pk.x = bfpack(a.x * s, a.y * s);
      pk.y = bfpack(a.z * s, a.w * s);
      outb[r * 16 + tx] = pk;   // row stride 16 uint2 = 128 B
    }
  }
}

// Layer-1 aggregate + relu + fused (h1 @ W2)*dinv epilogue. 4 groups x 16
// lanes; lane c covers bf16 cols 4c..4c+3 (uint2, 8 B). 4-edge unrolled
// inner loop: 16 independent row loads in flight per wave.
__launch_bounds__(256)
__global__ void k_agg64_w2(const uint2* __restrict__ hsb,    // [n*16] bf16 rows
                           const int* __restrict__ rp,
                           const int* __restrict__ col,
                           const float* __restrict__ dinv,
                           const float* __restrict__ b1,
                           const float* __restrict__ W2,     // 64x16
                           unsigned* __restrict__ hs2b,      // [n*8] bf16 rows
                           int n) {
  int lane = threadIdx.x & 63;
  int c = lane & 15;     // cols 4c..4c+3
  int sub = lane >> 4;   // group 0..3
  int node = (blockIdx.x * blockDim.x + threadIdx.x) >> 6;
  if (node >= n) return;

  float4 b14 = ((const float4*)b1)[c];
  float w2r[16];
  #pragma unroll
  for (int i = 0; i < 16; i++) w2r[i] = W2[(sub * 16 + i) * 16 + c];

  int s0 = rp[node], s1 = rp[node + 1];
  int dt = s1 - s0 + 1;  // virtual edge list: [self] + col[s0..s1)
  float ax = 0.f, ay = 0.f, az = 0.f, aw = 0.f;
  int t = sub;
  int i0 = 0, i1 = 0, i2 = 0, i3 = 0;
  if (t < dt)      i0 = (t == 0) ? node : col[s0 + t - 1];
  if (t + 4 < dt)  i1 = col[s0 + t + 3];
  if (t + 8 < dt)  i2 = col[s0 + t + 7];
  if (t + 12 < dt) i3 = col[s0 + t + 11];
  while (t < dt) {
    int c0 = i0, c1 = i1, c2 = i2, c3 = i3;
    bool h1 = (t + 4) < dt, h2 = (t + 8) < dt, h3 = (t + 12) < dt;
    int tn = t + 16;
    if (tn < dt)      i0 = col[s0 + tn - 1];
    if (tn + 4 < dt)  i1 = col[s0 + tn + 3];
    if (tn + 8 < dt)  i2 = col[s0 + tn + 7];
    if (tn + 12 < dt) i3 = col[s0 + tn + 11];
    uint2 u0 = hsb[c0 * 16 + c];
    uint2 u1 = h1 ? hsb[c1 * 16 + c] : make_uint2(0u, 0u);
    uint2 u2 = h2 ? hsb[c2 * 16 + c] : make_uint2(0u, 0u);
    uint2 u3 = h3 ? hsb[c3 * 16 + c] : make_uint2(0u, 0u);
    ax += __uint_as_float(u0.x << 16) + __uint_as_float(u1.x << 16)
        + __uint_as_float(u2.x << 16) + __uint_as_float(u3.x << 16);
    ay += __uint_as_float(u0.x & 0xffff0000u) + __uint_as_float(u1.x & 0xffff0000u)
        + __uint_as_float(u2.x & 0xffff0000u) + __uint_as_float(u3.x & 0xffff0000u);
    az += __uint_as_float(u0.y << 16) + __uint_as_float(u1.y << 16)
        + __uint_as_float(u2.y << 16) + __uint_as_float(u3.y << 16);
    aw += __uint_as_float(u0.y & 0xffff0000u) + __uint_as_float(u1.y & 0xffff0000u)
        + __uint_as_float(u2.y & 0xffff0000u) + __uint_as_float(u3.y & 0xffff0000u);
    t = tn;
  }
  #pragma unroll
  for (int m = 16; m <= 32; m <<= 1) {
    ax += __shfl_xor(ax, m);
    ay += __shfl_xor(ay, m);
    az += __shfl_xor(az, m);
    aw += __shfl_xor(aw, m);
  }
  float dv = dinv[node];
  float hx = fmaxf(ax * dv + b14.x, 0.f);
  float hy = fmaxf(ay * dv + b14.y, 0.f);
  float hz = fmaxf(az * dv + b14.z, 0.f);
  float hw = fmaxf(aw * dv + b14.w, 0.f);

  float part = 0.f;
  #pragma unroll
  for (int i = 0; i < 16; i++) {
    int srcLane = 4 * sub + (i >> 2);
    float h;
    if ((i & 3) == 0)      h = __shfl(hx, srcLane);
    else if ((i & 3) == 1) h = __shfl(hy, srcLane);
    else if ((i & 3) == 2) h = __shfl(hz, srcLane);
    else                   h = __shfl(hw, srcLane);
    part = fmaf(h, w2r[i], part);
  }
  #pragma unroll
  for (int m = 16; m <= 32; m <<= 1) part += __shfl_xor(part, m);
  part *= dv;
  // pack pairs of adjacent output cols to bf16; even-c lanes of group 0 write
  float pnext = __shfl_down(part, 1);
  if (sub == 0 && (c & 1) == 0) {
    hs2b[node * 8 + (c >> 1)] = bfpack(part, pnext);
  }
}

// Layer-2 aggregate: one wave per node, 16 groups x 4 lanes; uint2 bf16
// loads (row = 32 B), 2-edge unroll -> 32 rows in flight. Final output f32.
__launch_bounds__(256)
__global__ void k_agg16(const uint2* __restrict__ hs2b,    // [n*4] bf16 rows
                        const int* __restrict__ rp,
                        const int* __restrict__ col,
                        const float* __restrict__ dinv,
                        const float* __restrict__ b2,
                        float4* __restrict__ out4,          // [n*4]
                        int n) {
  int lane = threadIdx.x & 63;
  int c = lane & 3;      // cols 4c..4c+3
  int sub = lane >> 2;   // group 0..15
  int node = (blockIdx.x * blockDim.x + threadIdx.x) >> 6;
  if (node >= n) return;

  int s0 = rp[node], s1 = rp[node + 1];
  int dt = s1 - s0 + 1;
  float ax = 0.f, ay = 0.f, az = 0.f, aw = 0.f;
  int t = sub;
  int i0 = 0, i1 = 0;
  if (t < dt)      i0 = (t == 0) ? node : col[s0 + t - 1];
  if (t + 16 < dt) i1 = col[s0 + t + 15];
  while (t < dt) {
    int c0 = i0, c1 = i1;
    bool h1 = (t + 16) < dt;
    int tn = t + 32;
    if (tn < dt)      i0 = col[s0 + tn - 1];
    if (tn + 16 < dt) i1 = col[s0 + tn + 15];
    uint2 u0 = hs2b[c0 * 4 + c];
    uint2 u1 = h1 ? hs2b[c1 * 4 + c] : make_uint2(0u, 0u);
    ax += __uint_as_float(u0.x << 16) + __uint_as_float(u1.x << 16);
    ay += __uint_as_float(u0.x & 0xffff0000u) + __uint_as_float(u1.x & 0xffff0000u);
    az += __uint_as_float(u0.y << 16) + __uint_as_float(u1.y << 16);
    aw += __uint_as_float(u0.y & 0xffff0000u) + __uint_as_float(u1.y & 0xffff0000u);
    t = tn;
  }
  #pragma unroll
  for (int m = 4; m <= 32; m <<= 1) {
    ax += __shfl_xor(ax, m);
    ay += __shfl_xor(ay, m);
    az += __shfl_xor(az, m);
    aw += __shfl_xor(aw, m);
  }
  if (sub == 0) {
    float dv = dinv[node];
    float4 b24 = ((const float4*)b2)[c];
    float4 o;
    o.x = ax * dv + b24.x;
    o.y = ay * dv + b24.y;
    o.z = az * dv + b24.z;
    o.w = aw * dv + b24.w;
    out4[node * 4 + c] = o;
  }
}

extern "C" void kernel_launch(void* const* d_in, const int* in_sizes, int n_in,
                              void* d_out, int out_size, void* d_ws, size_t ws_size,
                              hipStream_t stream) {
  const float* x  = (const float*)d_in[0];
  const int* edges = (const int*)d_in[1];
  const float* W1 = (const float*)d_in[2];
  const float* b1 = (const float*)d_in[3];
  const float* W2 = (const float*)d_in[4];
  const float* b2 = (const float*)d_in[5];
  float* out = (float*)d_out;

  const int N = in_sizes[0] / 64;
  const int E = in_sizes[1] / 2;
  const int* src = edges;
  const int* dst = edges + E;
  const int NB = (N + BUCKET_NODES - 1) >> NBSHIFT;  // 147 <= MAXNB

  auto align = [](size_t v) { return (v + 255) & ~(size_t)255; };
  char* p = (char*)d_ws;
  float* dinv       = (float*)p; p += align((size_t)N * 4);
  int*   rp         = (int*)p;   p += align((size_t)(N + 1) * 4);
  int*   bucketCur  = (int*)p;   p += align((size_t)MAXNB * 4);
  int*   col        = (int*)p;   p += align((size_t)E * 4);
  float* hs1        = (float*)p; p += align((size_t)N * 64 * 4);  // bf16 rows use half
  float* hs2        = (float*)p; p += align((size_t)N * 16 * 4);  // bf16 rows use half
  // bucketArr (~6 MB) aliases hs1 region: pass A/B finish before k_gemm64
  // overwrites it (serial stream).
  int* bucketArr = (int*)hs1;

  const int nbA = (E + CHA - 1) / CHA;
  const int nbWave = ((size_t)N * 64 + 255) / 256;

  hipMemsetAsync(bucketCur, 0, (size_t)MAXNB * 4, stream);
  kA_bucket<<<nbA, TA, 0, stream>>>(src, dst, bucketCur, bucketArr, NB, E);
  kB_fill  <<<NB, TB, 0, stream>>>(bucketArr, bucketCur, rp, dinv, col, N, NB);

  k_gemm64  <<<(N + 63) / 64, 256, 0, stream>>>((const float4*)x, (const float4*)W1,
                                                dinv, (uint2*)hs1, N);
  k_agg64_w2<<<nbWave, 256, 0, stream>>>((const uint2*)hs1, rp, col, dinv,
                                         b1, W2, (unsigned*)hs2, N);
  k_agg16   <<<nbWave, 256, 0, stream>>>((const uint2*)hs2, rp, col, dinv,
                                         b2, (float4*)out, N);
}